// Round 6
// baseline (13.733 us; speedup 1.0000x reference)
//
#include <hip/hip_runtime.h>
#include <math.h>

constexpr int NB = 8;    // batch
constexpr int NF = 32;   // features
constexpr int NN = 512;  // nodes
constexpr int NH = 8;    // hidden
constexpr int JC = 32;   // columns per block
constexpr int IR = 256;  // rows per block (half the node range)

// ---------------------------------------------------------------------------
// Single fused kernel. Block = (jc, ih, b) owns out[b, ih*256..+255, jc*32..+31].
//   waves 4-7: float4 colsum partials of adj[0] for its 32 cols -> cs_lds
//   waves 0-3: u[k][i] for its 256 rows -> u_lds   (u = emb . W1[:F])
//   32 thr:    v[k][j] for its 32 cols  -> v_lds   (v = emb . W1[F:2F]
//                                                   + sw*W1[2F] + b1)
//   all:       out[b,i,j] = sigmoid(b2 + sum_k relu(u+v)*W2), float4 stores
// Redundancy: colsum x16, u x16 -- all L2-resident (adj[0]=1MB, emb=512KB).
// ---------------------------------------------------------------------------
__global__ __launch_bounds__(512) void fused1_kernel(
    const float* __restrict__ adj, const float* __restrict__ emb,
    const float* __restrict__ W1, const float* __restrict__ b1,
    const float* __restrict__ W2, const float* __restrict__ b2,
    float* __restrict__ out)
{
    __shared__ float  u_lds[NH][IR];    // 8 KB
    __shared__ float  v_lds[NH][JC];    // 1 KB
    __shared__ float4 cs_lds[32][8];    // 4 KB   [row-group][col-quad]

    const int jc = blockIdx.x;        // [0,16)
    const int ih = blockIdx.y;        // [0,2)
    const int b  = blockIdx.z;        // [0,8)
    const int j0 = jc * JC;
    const int i0 = ih * IR;
    const int t  = threadIdx.x;       // [0,512)

    if (t < 256) {
        // ---- u for rows i0 .. i0+255 (coalesced emb reads) ----
        const int i = i0 + t;
        float uo[NH];
        #pragma unroll
        for (int k = 0; k < NH; ++k) uo[k] = 0.f;
        #pragma unroll 8
        for (int f = 0; f < NF; ++f) {
            const float e = emb[((size_t)b * NF + f) * NN + i];
            #pragma unroll
            for (int k = 0; k < NH; ++k)
                uo[k] = fmaf(e, W1[f * NH + k], uo[k]);   // W1 wave-uniform
        }
        #pragma unroll
        for (int k = 0; k < NH; ++k) u_lds[k][t] = uo[k];
    } else {
        // ---- colsum partials: float4 over 4 cols, 16 rows per thread ----
        const int tt = t - 256;
        const int c4 = tt & 7;            // col quad [0,8)
        const int rg = tt >> 3;           // row group [0,32)
        const float4* p = reinterpret_cast<const float4*>(
            adj + (size_t)(rg * 16) * NN + j0 + c4 * 4);
        float4 acc = make_float4(0.f, 0.f, 0.f, 0.f);
        #pragma unroll 16
        for (int r = 0; r < 16; ++r) {
            const float4 x = p[(size_t)r * (NN / 4)];
            acc.x += x.x; acc.y += x.y; acc.z += x.z; acc.w += x.w;
        }
        cs_lds[rg][c4] = acc;
    }
    __syncthreads();

    if (t >= 256 && t < 256 + JC) {
        // ---- finalize sw + v for the 32 columns ----
        const int c = t - 256;
        const int n = j0 + c;
        float cs = 0.f;
        #pragma unroll
        for (int rg = 0; rg < 32; ++rg) {
            const float4 q = cs_lds[rg][c >> 2];
            cs += (c & 3) == 0 ? q.x : (c & 3) == 1 ? q.y : (c & 3) == 2 ? q.z : q.w;
        }
        const float dg = adj[((size_t)b * NN + n) * NN + n];
        const float sw = (cs - dg) * (1.0f / (float)(NN - 1));

        float vo[NH];
        #pragma unroll
        for (int k = 0; k < NH; ++k)
            vo[k] = b1[k] + sw * W1[2 * NF * NH + k];
        #pragma unroll 8
        for (int f = 0; f < NF; ++f) {
            const float e = emb[((size_t)b * NF + f) * NN + n];
            #pragma unroll
            for (int k = 0; k < NH; ++k)
                vo[k] = fmaf(e, W1[(NF + f) * NH + k], vo[k]);
        }
        #pragma unroll
        for (int k = 0; k < NH; ++k) v_lds[k][c] = vo[k];
    }
    __syncthreads();

    // ---- output sweep: thread owns 4 consecutive j, 4 rows; float4 stores ----
    float w2[NH];
    #pragma unroll
    for (int k = 0; k < NH; ++k) w2[k] = W2[k];
    const float bias = b2[0];

    const int j4 = (t & 7) * 4;       // col quad start
    const int ig = t >> 3;            // [0,64) -> 4 rows each

    float4 vv[NH];
    #pragma unroll
    for (int k = 0; k < NH; ++k)
        vv[k] = *reinterpret_cast<const float4*>(&v_lds[k][j4]);

    float* obase = out + ((size_t)b * NN + i0) * NN + j0 + j4;
    #pragma unroll
    for (int r = 0; r < 4; ++r) {
        const int i = ig * 4 + r;
        float4 a = make_float4(bias, bias, bias, bias);
        #pragma unroll
        for (int k = 0; k < NH; ++k) {
            const float uk = u_lds[k][i];         // 8-way broadcast, bank-clean
            a.x = fmaf(fmaxf(uk + vv[k].x, 0.f), w2[k], a.x);
            a.y = fmaf(fmaxf(uk + vv[k].y, 0.f), w2[k], a.y);
            a.z = fmaf(fmaxf(uk + vv[k].z, 0.f), w2[k], a.z);
            a.w = fmaf(fmaxf(uk + vv[k].w, 0.f), w2[k], a.w);
        }
        float4 o;
        o.x = __builtin_amdgcn_rcpf(1.0f + __expf(-a.x));
        o.y = __builtin_amdgcn_rcpf(1.0f + __expf(-a.y));
        o.z = __builtin_amdgcn_rcpf(1.0f + __expf(-a.z));
        o.w = __builtin_amdgcn_rcpf(1.0f + __expf(-a.w));
        *reinterpret_cast<float4*>(obase + (size_t)i * NN) = o;  // 1KB/wave-instr
    }
}

extern "C" void kernel_launch(void* const* d_in, const int* in_sizes, int n_in,
                              void* d_out, int out_size, void* d_ws, size_t ws_size,
                              hipStream_t stream) {
    const float* adj = (const float*)d_in[0];
    const float* emb = (const float*)d_in[1];
    const float* W1  = (const float*)d_in[2];
    const float* b1  = (const float*)d_in[3];
    const float* W2  = (const float*)d_in[4];
    const float* b2  = (const float*)d_in[5];
    float* out = (float*)d_out;

    fused1_kernel<<<dim3(NN / JC, NN / IR, NB), 512, 0, stream>>>(
        adj, emb, W1, b1, W2, b2, out);
}

// Round 7
// 11.870 us; speedup vs baseline: 1.1570x; 1.1570x over previous
//
#include <hip/hip_runtime.h>
#include <math.h>

constexpr int NB = 8;    // batch
constexpr int NF = 32;   // features
constexpr int NN = 512;  // nodes
constexpr int NH = 8;    // hidden
constexpr int JC = 32;   // columns per block
constexpr int IR = 256;  // rows per block (half the node range)

// ---------------------------------------------------------------------------
// Single fused kernel (R5 structure; only change vs R5: sigmoid via rcp).
// Block = (jc, ih, b) owns out[b, ih*256..+255, jc*32..+31].
//   waves 4-7: colsum partials of adj[0] for its 32 columns -> cs_lds
//   waves 0-3: u[k][i] for its 256 rows -> u_lds   (u = emb . W1[:F])
//   32 thr:    v[k][j] for its 32 cols  -> v_lds   (v = emb . W1[F:2F]
//                                                   + sw*W1[2F] + b1)
//   all:       out[b,i,j] = sigmoid(b2 + sum_k relu(u+v)*W2)
// Grid = 256 blocks on 256 CUs (1 block/CU).
// ---------------------------------------------------------------------------
__global__ __launch_bounds__(512) void fused1_kernel(
    const float* __restrict__ adj, const float* __restrict__ emb,
    const float* __restrict__ W1, const float* __restrict__ b1,
    const float* __restrict__ W2, const float* __restrict__ b2,
    float* __restrict__ out)
{
    __shared__ float u_lds[NH][IR];   // 8 KB
    __shared__ float v_lds[NH][JC];   // 1 KB
    __shared__ float cs_lds[8][JC];   // 1 KB

    const int jc = blockIdx.x;        // [0,16)
    const int ih = blockIdx.y;        // [0,2)
    const int b  = blockIdx.z;        // [0,8)
    const int j0 = jc * JC;
    const int i0 = ih * IR;
    const int t  = threadIdx.x;       // [0,512)

    if (t < 256) {
        // ---- u for rows i0 .. i0+255 (coalesced emb reads) ----
        const int i = i0 + t;
        float uo[NH];
        #pragma unroll
        for (int k = 0; k < NH; ++k) uo[k] = 0.f;
        #pragma unroll 8
        for (int f = 0; f < NF; ++f) {
            const float e = emb[((size_t)b * NF + f) * NN + i];
            #pragma unroll
            for (int k = 0; k < NH; ++k)
                uo[k] = fmaf(e, W1[f * NH + k], uo[k]);   // W1 wave-uniform
        }
        #pragma unroll
        for (int k = 0; k < NH; ++k) u_lds[k][t] = uo[k]; // bank=t%32, clean
    } else {
        // ---- colsum partials: 32 cols x 8 row-groups of 64 rows ----
        const int tt = t - 256;
        const int c  = tt & 31;
        const int rg = tt >> 5;                           // [0,8)
        const float* p = adj + (size_t)(rg * 64) * NN + j0 + c;
        float acc = 0.f;
        #pragma unroll 16
        for (int r = 0; r < 64; ++r)
            acc += p[(size_t)r * NN];                     // 128B segs
        cs_lds[rg][c] = acc;
    }
    __syncthreads();

    if (t >= 256 && t < 256 + JC) {
        // ---- finalize sw + v for the 32 columns ----
        const int c = t - 256;
        const int n = j0 + c;
        float cs = 0.f;
        #pragma unroll
        for (int rg = 0; rg < 8; ++rg) cs += cs_lds[rg][c];
        const float dg = adj[((size_t)b * NN + n) * NN + n];
        const float sw = (cs - dg) * (1.0f / (float)(NN - 1));

        float vo[NH];
        #pragma unroll
        for (int k = 0; k < NH; ++k)
            vo[k] = b1[k] + sw * W1[2 * NF * NH + k];
        #pragma unroll 8
        for (int f = 0; f < NF; ++f) {
            const float e = emb[((size_t)b * NF + f) * NN + n];
            #pragma unroll
            for (int k = 0; k < NH; ++k)
                vo[k] = fmaf(e, W1[(NF + f) * NH + k], vo[k]);
        }
        #pragma unroll
        for (int k = 0; k < NH; ++k) v_lds[k][c] = vo[k];
    }
    __syncthreads();

    // ---- output sweep: thread owns column j, 16 rows ----
    float w2[NH];
    #pragma unroll
    for (int k = 0; k < NH; ++k) w2[k] = W2[k];
    const float bias = b2[0];

    const int j    = t & 31;
    const int isub = t >> 5;                              // [0,16)

    float vv[NH];
    #pragma unroll
    for (int k = 0; k < NH; ++k) vv[k] = v_lds[k][j];     // bank-clean

    float* orow = out + ((size_t)b * NN + i0) * NN + j0 + j;
    #pragma unroll 4
    for (int r = 0; r < 16; ++r) {
        const int i = isub * 16 + r;
        float a = bias;
        #pragma unroll
        for (int k = 0; k < NH; ++k)
            a = fmaf(fmaxf(u_lds[k][i] + vv[k], 0.f), w2[k], a);  // 2-addr bcast
        orow[(size_t)i * NN] = __builtin_amdgcn_rcpf(1.0f + __expf(-a));
    }
}

extern "C" void kernel_launch(void* const* d_in, const int* in_sizes, int n_in,
                              void* d_out, int out_size, void* d_ws, size_t ws_size,
                              hipStream_t stream) {
    const float* adj = (const float*)d_in[0];
    const float* emb = (const float*)d_in[1];
    const float* W1  = (const float*)d_in[2];
    const float* b1  = (const float*)d_in[3];
    const float* W2  = (const float*)d_in[4];
    const float* b2  = (const float*)d_in[5];
    float* out = (float*)d_out;

    fused1_kernel<<<dim3(NN / JC, NN / IR, NB), 512, 0, stream>>>(
        adj, emb, W1, b1, W2, b2, out);
}